// Round 1
// baseline (157.639 us; speedup 1.0000x reference)
//
#include <hip/hip_runtime.h>

#define NC 320   // coalition size
#define DIM 512

// ---------------------------------------------------------------------------
// q = x @ Wq^T + bq ; k = x @ Wk^T + bk   (blockIdx.z selects which)
// Tiled fp32 GEMM, C[m,n] = sum_e A[m,e]*B[n,e] + bias[n]; 64x64 tile, BK=16,
// 256 threads, 4x4 micro-tile, LDS transposed with +4 pad for b128 reads.
// ---------------------------------------------------------------------------
__global__ __launch_bounds__(256) void gemm_qk(
    const float* __restrict__ x,
    const float* __restrict__ Wq, const float* __restrict__ bq,
    const float* __restrict__ Wk, const float* __restrict__ bk,
    float* __restrict__ qout, float* __restrict__ kout)
{
  const float* __restrict__ W    = blockIdx.z ? Wk : Wq;
  const float* __restrict__ bias = blockIdx.z ? bk : bq;
  float* __restrict__ out        = blockIdx.z ? kout : qout;

  __shared__ __align__(16) float As[16][68];
  __shared__ __align__(16) float Bs[16][68];

  const int t  = threadIdx.x;
  const int tx = t & 15;        // n dir
  const int ty = t >> 4;        // m dir
  const int rowbase = blockIdx.y * 64;
  const int colbase = blockIdx.x * 64;
  const int lr = t >> 2;        // 0..63  (tile row loaded by this thread)
  const int lc = (t & 3) << 2;  // 0,4,8,12 (k-offset within BK)

  float acc[4][4] = {};

  for (int k0 = 0; k0 < DIM; k0 += 16) {
    const float4 av = *(const float4*)&x[(rowbase + lr) * DIM + k0 + lc];
    const float4 bv = *(const float4*)&W[(colbase + lr) * DIM + k0 + lc];
    __syncthreads();
    As[lc+0][lr] = av.x; As[lc+1][lr] = av.y; As[lc+2][lr] = av.z; As[lc+3][lr] = av.w;
    Bs[lc+0][lr] = bv.x; Bs[lc+1][lr] = bv.y; Bs[lc+2][lr] = bv.z; Bs[lc+3][lr] = bv.w;
    __syncthreads();
    #pragma unroll
    for (int kk = 0; kk < 16; ++kk) {
      const float4 a4 = *(const float4*)&As[kk][ty*4];
      const float4 b4 = *(const float4*)&Bs[kk][tx*4];
      const float a[4] = {a4.x, a4.y, a4.z, a4.w};
      const float b[4] = {b4.x, b4.y, b4.z, b4.w};
      #pragma unroll
      for (int i = 0; i < 4; ++i)
        #pragma unroll
        for (int j = 0; j < 4; ++j)
          acc[i][j] = fmaf(a[i], b[j], acc[i][j]);
    }
  }

  const float4 bia = *(const float4*)&bias[colbase + tx*4];
  #pragma unroll
  for (int i = 0; i < 4; ++i) {
    const int row = rowbase + ty*4 + i;
    float4 o;
    o.x = acc[i][0] + bia.x; o.y = acc[i][1] + bia.y;
    o.z = acc[i][2] + bia.z; o.w = acc[i][3] + bia.w;
    *(float4*)&out[row * DIM + colbase + tx*4] = o;
  }
}

// ---------------------------------------------------------------------------
// h[e] = sum_d Wv[d,e] * wA[d]   (wA = Wc[0, 0:512])
// grid (2, 16): x covers e (coalesced), y splits d into 32-chunks; atomicAdd.
// ---------------------------------------------------------------------------
__global__ __launch_bounds__(256) void compute_h(
    const float* __restrict__ Wv, const float* __restrict__ Wc,
    float* __restrict__ h)
{
  const int e  = blockIdx.x * 256 + threadIdx.x;  // 0..511
  const int d0 = blockIdx.y * 32;
  float s = 0.f;
  #pragma unroll
  for (int d = 0; d < 32; ++d)
    s = fmaf(Wv[(d0 + d) * DIM + e], Wc[d0 + d], s);
  atomicAdd(&h[e], s);
}

// ---------------------------------------------------------------------------
// One block (256 thr) per query row i:
//   scores[i,kk] = q[i]·k[kk]/sqrt(D)  (wave-parallel dots)
//   e = exp(scores - rowmax); S = prefix sums; W[j]=1/(j*S[j]) for j>i;
//   Csuf[m] = sum_{j>=m} W[j];  P[kk] += e[kk]*Csuf[max(i,kk)+1]
// ---------------------------------------------------------------------------
__global__ __launch_bounds__(256) void attn_row(
    const float* __restrict__ q, const float* __restrict__ k,
    float* __restrict__ P)
{
  const int i    = blockIdx.x;
  const int t    = threadIdx.x;
  const int lane = t & 63;
  const int wave = t >> 6;

  __shared__ __align__(16) float qs[DIM];
  __shared__ float e[NC];
  __shared__ float Warr[NC];
  __shared__ float Csuf[NC + 1];
  __shared__ float wred[4];

  for (int idx = t; idx < DIM; idx += 256) qs[idx] = q[i * DIM + idx];
  __syncthreads();

  // --- scores: each wave handles kk = wave, wave+4, ... (80 dots/wave) ---
  const float4* q4 = (const float4*)qs;
  for (int kk = wave; kk < NC; kk += 4) {
    const float4* k4 = (const float4*)(k + kk * DIM);
    float s = 0.f;
    #pragma unroll
    for (int m = 0; m < 2; ++m) {
      const float4 kv = k4[lane + 64 * m];
      const float4 qv = q4[lane + 64 * m];
      s += qv.x * kv.x + qv.y * kv.y + qv.z * kv.z + qv.w * kv.w;
    }
    #pragma unroll
    for (int off = 32; off; off >>= 1) s += __shfl_down(s, off);
    if (lane == 0) e[kk] = s * 0.044194173824159216f;  // 1/sqrt(512)
  }
  __syncthreads();

  // --- row max (valid shift for every prefix softmax) ---
  float m = -1e30f;
  for (int kk = t; kk < NC; kk += 256) m = fmaxf(m, e[kk]);
  #pragma unroll
  for (int off = 32; off; off >>= 1) m = fmaxf(m, __shfl_down(m, off));
  if (lane == 0) wred[wave] = m;
  __syncthreads();   // also orders: all e-reads above before e-writes below
  m = fmaxf(fmaxf(wred[0], wred[1]), fmaxf(wred[2], wred[3]));

  for (int kk = t; kk < NC; kk += 256) e[kk] = __expf(e[kk] - m);
  __syncthreads();

  // --- wave 0: forward scan -> W, reverse scan -> Csuf ---
  if (wave == 0) {
    float carry = 0.f;
    #pragma unroll
    for (int c = 0; c < 5; ++c) {
      const int idx = c * 64 + lane;
      float val = e[idx];
      #pragma unroll
      for (int off = 1; off < 64; off <<= 1) {
        const float nv = __shfl_up(val, off);
        if (lane >= off) val += nv;
      }
      const float incl = val + carry;       // S[idx+1]
      const int j = idx + 1;
      if (j < NC) Warr[j] = (j > i) ? 1.f / ((float)j * incl) : 0.f;
      carry += __shfl(val, 63);
    }
    if (lane == 0) Warr[0] = 0.f;

    carry = 0.f;
    #pragma unroll
    for (int c = 4; c >= 0; --c) {
      const int idx = c * 64 + lane;
      float val = Warr[idx];
      #pragma unroll
      for (int off = 1; off < 64; off <<= 1) {
        const float nv = __shfl_down(val, off);
        if (lane + off < 64) val += nv;
      }
      Csuf[idx] = val + carry;              // sum_{j>=idx} W[j]
      carry += __shfl(val, 0);
    }
    if (lane == 0) Csuf[NC] = 0.f;
  }
  __syncthreads();

  // --- P[kk] += e[kk] * C[max(i,kk)]  (C[m] = Csuf[m+1]) ---
  for (int kk = t; kk < NC; kk += 256) {
    const int mm = (i > kk) ? i : kk;
    atomicAdd(&P[kk], e[kk] * Csuf[mm + 1]);
  }
}

// ---------------------------------------------------------------------------
// out = sum_kk sum_e x[kk,e]*(P[kk]*h[e] + wx[e]) + (bv·wA)*(sum P) + NC*bc
// wx = Wc[0, 512:1024]. One block per kk; block 0 adds the extras.
// ---------------------------------------------------------------------------
__global__ __launch_bounds__(256) void finalize(
    const float* __restrict__ x, const float* __restrict__ P,
    const float* __restrict__ h, const float* __restrict__ Wc,
    const float* __restrict__ bc, const float* __restrict__ bv,
    float* __restrict__ out)
{
  const int kk   = blockIdx.x;
  const int t    = threadIdx.x;
  const int lane = t & 63;
  const int wave = t >> 6;

  __shared__ float tmp[4];
  __shared__ float tmp2[8];

  const float pk = P[kk];
  const float* xr = x + kk * DIM;
  float s = 0.f;
  for (int e = t; e < DIM; e += 256)
    s += xr[e] * fmaf(pk, h[e], Wc[DIM + e]);
  #pragma unroll
  for (int off = 32; off; off >>= 1) s += __shfl_down(s, off);
  if (lane == 0) tmp[wave] = s;

  if (kk == 0) {
    float ec = 0.f, ep = 0.f;
    for (int d = t; d < DIM; d += 256) ec += bv[d] * Wc[d];
    for (int mIdx = t; mIdx < NC; mIdx += 256) ep += P[mIdx];
    #pragma unroll
    for (int off = 32; off; off >>= 1) {
      ec += __shfl_down(ec, off);
      ep += __shfl_down(ep, off);
    }
    if (lane == 0) { tmp2[wave] = ec; tmp2[4 + wave] = ep; }
  }
  __syncthreads();

  if (t == 0) {
    float tot = tmp[0] + tmp[1] + tmp[2] + tmp[3];
    atomicAdd(out, tot);
    if (kk == 0) {
      const float c  = tmp2[0] + tmp2[1] + tmp2[2] + tmp2[3];
      const float sp = tmp2[4] + tmp2[5] + tmp2[6] + tmp2[7];
      atomicAdd(out, c * sp + (float)NC * bc[0]);
    }
  }
}

// ---------------------------------------------------------------------------
extern "C" void kernel_launch(void* const* d_in, const int* in_sizes, int n_in,
                              void* d_out, int out_size, void* d_ws, size_t ws_size,
                              hipStream_t stream) {
  const float* x  = (const float*)d_in[0];
  // d_in[1] = goal (unused by the reference forward)
  const float* Wq = (const float*)d_in[2];
  const float* bq = (const float*)d_in[3];
  const float* Wk = (const float*)d_in[4];
  const float* bk = (const float*)d_in[5];
  const float* Wv = (const float*)d_in[6];
  const float* bv = (const float*)d_in[7];
  const float* Wc = (const float*)d_in[8];
  const float* bc = (const float*)d_in[9];

  float* ws = (float*)d_ws;
  float* q  = ws;                 // 320*512
  float* k  = ws + NC * DIM;      // 320*512
  float* P  = ws + 2 * NC * DIM;  // 320
  float* h  = P + NC;             // 512
  float* out = (float*)d_out;

  // P, h, out must be zeroed every call (harness poisons ws/out with 0xAA)
  hipMemsetAsync(P, 0, (NC + DIM) * sizeof(float), stream);
  hipMemsetAsync(out, 0, sizeof(float), stream);

  gemm_qk<<<dim3(8, 5, 2), 256, 0, stream>>>(x, Wq, bq, Wk, bk, q, k);
  compute_h<<<dim3(2, 16), 256, 0, stream>>>(Wv, Wc, h);
  attn_row<<<NC, 256, 0, stream>>>(q, k, P);
  finalize<<<NC, 256, 0, stream>>>(x, P, h, Wc, bc, bv, out);
}

// Round 2
// 129.585 us; speedup vs baseline: 1.2165x; 1.2165x over previous
//
#include <hip/hip_runtime.h>

#define NC 320   // coalition size
#define DIM 512

// ---------------------------------------------------------------------------
// q = x @ Wq^T + bq ; k = x @ Wk^T + bk   (blockIdx.z selects which)
// Tile: 16 rows x 64 cols, BK=64. grid (8, 20, 2) = 320 blocks, 256 threads.
// A staged transposed As[kk][row] -> broadcast b128 fragment reads;
// Bs[kk][col] -> conflict-free (2-way) b32 reads. 4 FMA / kk / thread.
// __launch_bounds__(256,2): 2 blocks/CU (LDS 22.5KB) for latency hiding.
// ---------------------------------------------------------------------------
__global__ __launch_bounds__(256, 2) void gemm_qk2(
    const float* __restrict__ x,
    const float* __restrict__ Wq, const float* __restrict__ bq,
    const float* __restrict__ Wk, const float* __restrict__ bk,
    float* __restrict__ qout, float* __restrict__ kout)
{
  const float* __restrict__ W    = blockIdx.z ? Wk : Wq;
  const float* __restrict__ bias = blockIdx.z ? bk : bq;
  float* __restrict__ out        = blockIdx.z ? kout : qout;
  const int i0 = blockIdx.y * 16;   // row tile (of 320)
  const int c0 = blockIdx.x * 64;   // col tile (of 512)

  __shared__ __align__(16) float As[64][20];  // [kk][row], 80B row stride (16B-aligned)
  __shared__ __align__(16) float Bs[64][68];  // [kk][col]

  const int t = threadIdx.x;
  // staging roles
  const int sr  = t >> 4;          // 0..15 row for As
  const int skc = (t & 15) * 4;    // kk base for As
  const int sc  = t >> 2;          // 0..63 col for Bs
  const int skg = t & 3;           // kk quarter for Bs
  // compute roles
  const int rq = t >> 6;           // 0..3 row quad
  const int cc = t & 63;           // 0..63 col

  float4 acc = {0.f, 0.f, 0.f, 0.f};
  const float bias_c = bias[c0 + cc];

  const float* xrow = x + (i0 + sr) * DIM + skc;
  const float* wrow = W + (c0 + sc) * DIM + skg * 16;

  for (int k0 = 0; k0 < DIM; k0 += 64) {
    const float4 av = *(const float4*)(xrow + k0);
    float4 wv[4];
    #pragma unroll
    for (int s4 = 0; s4 < 4; ++s4)
      wv[s4] = *(const float4*)(wrow + k0 + s4 * 4);
    __syncthreads();
    As[skc+0][sr] = av.x; As[skc+1][sr] = av.y;
    As[skc+2][sr] = av.z; As[skc+3][sr] = av.w;
    #pragma unroll
    for (int s4 = 0; s4 < 4; ++s4) {
      const int kb = skg * 16 + s4 * 4;
      Bs[kb+0][sc] = wv[s4].x; Bs[kb+1][sc] = wv[s4].y;
      Bs[kb+2][sc] = wv[s4].z; Bs[kb+3][sc] = wv[s4].w;
    }
    __syncthreads();
    #pragma unroll 16
    for (int kk = 0; kk < 64; ++kk) {
      const float4 a4 = *(const float4*)&As[kk][rq * 4];
      const float  b  = Bs[kk][cc];
      acc.x = fmaf(a4.x, b, acc.x);
      acc.y = fmaf(a4.y, b, acc.y);
      acc.z = fmaf(a4.z, b, acc.z);
      acc.w = fmaf(a4.w, b, acc.w);
    }
  }
  const int r0 = i0 + rq * 4;
  out[(r0+0)*DIM + c0+cc] = acc.x + bias_c;
  out[(r0+1)*DIM + c0+cc] = acc.y + bias_c;
  out[(r0+2)*DIM + c0+cc] = acc.z + bias_c;
  out[(r0+3)*DIM + c0+cc] = acc.w + bias_c;
}

// ---------------------------------------------------------------------------
// S[i][j] = (q[i]·k[j]) / sqrt(D). Tile 16x16, BK=64, grid (20,20)=400 blocks.
// One output per thread; kk inner loop vectorized float4 (2x b128 + 4 FMA).
// ---------------------------------------------------------------------------
__global__ __launch_bounds__(256, 2) void scores(
    const float* __restrict__ q, const float* __restrict__ k,
    float* __restrict__ S)
{
  const int i0 = blockIdx.y * 16, j0 = blockIdx.x * 16;
  __shared__ __align__(16) float qs[16][68];
  __shared__ __align__(16) float ks[16][68];
  const int t = threadIdx.x;
  const int sr = t >> 4, skc = (t & 15) * 4;   // staging
  const int r  = t >> 4, c  = t & 15;          // compute

  float acc = 0.f;
  const float* qrow = q + (i0 + sr) * DIM + skc;
  const float* krow = k + (j0 + sr) * DIM + skc;

  for (int k0 = 0; k0 < DIM; k0 += 64) {
    const float4 qv = *(const float4*)(qrow + k0);
    const float4 kv = *(const float4*)(krow + k0);
    __syncthreads();
    *(float4*)&qs[sr][skc] = qv;
    *(float4*)&ks[sr][skc] = kv;
    __syncthreads();
    #pragma unroll
    for (int kk = 0; kk < 64; kk += 4) {
      const float4 a = *(const float4*)&qs[r][kk];
      const float4 b = *(const float4*)&ks[c][kk];
      acc = fmaf(a.x, b.x, acc);
      acc = fmaf(a.y, b.y, acc);
      acc = fmaf(a.z, b.z, acc);
      acc = fmaf(a.w, b.w, acc);
    }
  }
  S[(i0 + r) * NC + (j0 + c)] = acc * 0.044194173824159216f;  // 1/sqrt(512)
}

// ---------------------------------------------------------------------------
// h[e] = sum_d Wv[d,e] * wA[d]   (wA = Wc[0, 0:512])
// ---------------------------------------------------------------------------
__global__ __launch_bounds__(256) void compute_h(
    const float* __restrict__ Wv, const float* __restrict__ Wc,
    float* __restrict__ h)
{
  const int e  = blockIdx.x * 256 + threadIdx.x;  // 0..511
  const int d0 = blockIdx.y * 32;
  float s = 0.f;
  #pragma unroll
  for (int d = 0; d < 32; ++d)
    s = fmaf(Wv[(d0 + d) * DIM + e], Wc[d0 + d], s);
  atomicAdd(&h[e], s);
}

// ---------------------------------------------------------------------------
// One block per query row i, e[] read from precomputed S:
//   e = exp(S[i,:] - rowmax); prefix sums -> W[j]=1/(j*S[j]) for j>i;
//   Csuf[m] = sum_{j>=m} W[j];  P[kk] += e[kk]*Csuf[max(i,kk)+1]
// (scan logic verbatim from the verified round-1 kernel)
// ---------------------------------------------------------------------------
__global__ __launch_bounds__(256) void row_ops(
    const float* __restrict__ S, float* __restrict__ P)
{
  const int i    = blockIdx.x;
  const int t    = threadIdx.x;
  const int lane = t & 63;
  const int wave = t >> 6;

  __shared__ float e[NC];
  __shared__ float Warr[NC];
  __shared__ float Csuf[NC + 1];
  __shared__ float wred[4];

  for (int kk = t; kk < NC; kk += 256) e[kk] = S[i * NC + kk];
  __syncthreads();

  // --- row max (valid shift for every prefix softmax) ---
  float m = -1e30f;
  for (int kk = t; kk < NC; kk += 256) m = fmaxf(m, e[kk]);
  #pragma unroll
  for (int off = 32; off; off >>= 1) m = fmaxf(m, __shfl_down(m, off));
  if (lane == 0) wred[wave] = m;
  __syncthreads();
  m = fmaxf(fmaxf(wred[0], wred[1]), fmaxf(wred[2], wred[3]));

  for (int kk = t; kk < NC; kk += 256) e[kk] = __expf(e[kk] - m);
  __syncthreads();

  // --- wave 0: forward scan -> W, reverse scan -> Csuf ---
  if (wave == 0) {
    float carry = 0.f;
    #pragma unroll
    for (int c = 0; c < 5; ++c) {
      const int idx = c * 64 + lane;
      float val = e[idx];
      #pragma unroll
      for (int off = 1; off < 64; off <<= 1) {
        const float nv = __shfl_up(val, off);
        if (lane >= off) val += nv;
      }
      const float incl = val + carry;       // S[idx+1]
      const int j = idx + 1;
      if (j < NC) Warr[j] = (j > i) ? 1.f / ((float)j * incl) : 0.f;
      carry += __shfl(val, 63);
    }
    if (lane == 0) Warr[0] = 0.f;

    carry = 0.f;
    #pragma unroll
    for (int c = 4; c >= 0; --c) {
      const int idx = c * 64 + lane;
      float val = Warr[idx];
      #pragma unroll
      for (int off = 1; off < 64; off <<= 1) {
        const float nv = __shfl_down(val, off);
        if (lane + off < 64) val += nv;
      }
      Csuf[idx] = val + carry;              // sum_{j>=idx} W[j]
      carry += __shfl(val, 0);
    }
    if (lane == 0) Csuf[NC] = 0.f;
  }
  __syncthreads();

  for (int kk = t; kk < NC; kk += 256) {
    const int mm = (i > kk) ? i : kk;
    atomicAdd(&P[kk], e[kk] * Csuf[mm + 1]);
  }
}

// ---------------------------------------------------------------------------
// out = sum_kk sum_e x[kk,e]*(P[kk]*h[e] + wx[e]) + (bv·wA)*(sum P) + NC*bc
// ---------------------------------------------------------------------------
__global__ __launch_bounds__(256) void finalize(
    const float* __restrict__ x, const float* __restrict__ P,
    const float* __restrict__ h, const float* __restrict__ Wc,
    const float* __restrict__ bc, const float* __restrict__ bv,
    float* __restrict__ out)
{
  const int kk   = blockIdx.x;
  const int t    = threadIdx.x;
  const int lane = t & 63;
  const int wave = t >> 6;

  __shared__ float tmp[4];
  __shared__ float tmp2[8];

  const float pk = P[kk];
  const float* xr = x + kk * DIM;
  float s = 0.f;
  for (int e = t; e < DIM; e += 256)
    s += xr[e] * fmaf(pk, h[e], Wc[DIM + e]);
  #pragma unroll
  for (int off = 32; off; off >>= 1) s += __shfl_down(s, off);
  if (lane == 0) tmp[wave] = s;

  if (kk == 0) {
    float ec = 0.f, ep = 0.f;
    for (int d = t; d < DIM; d += 256) ec += bv[d] * Wc[d];
    for (int mIdx = t; mIdx < NC; mIdx += 256) ep += P[mIdx];
    #pragma unroll
    for (int off = 32; off; off >>= 1) {
      ec += __shfl_down(ec, off);
      ep += __shfl_down(ep, off);
    }
    if (lane == 0) { tmp2[wave] = ec; tmp2[4 + wave] = ep; }
  }
  __syncthreads();

  if (t == 0) {
    float tot = tmp[0] + tmp[1] + tmp[2] + tmp[3];
    atomicAdd(out, tot);
    if (kk == 0) {
      const float c  = tmp2[0] + tmp2[1] + tmp2[2] + tmp2[3];
      const float sp = tmp2[4] + tmp2[5] + tmp2[6] + tmp2[7];
      atomicAdd(out, c * sp + (float)NC * bc[0]);
    }
  }
}

// ---------------------------------------------------------------------------
extern "C" void kernel_launch(void* const* d_in, const int* in_sizes, int n_in,
                              void* d_out, int out_size, void* d_ws, size_t ws_size,
                              hipStream_t stream) {
  const float* x  = (const float*)d_in[0];
  // d_in[1] = goal (unused by the reference forward)
  const float* Wq = (const float*)d_in[2];
  const float* bq = (const float*)d_in[3];
  const float* Wk = (const float*)d_in[4];
  const float* bk = (const float*)d_in[5];
  const float* Wv = (const float*)d_in[6];
  const float* bv = (const float*)d_in[7];
  const float* Wc = (const float*)d_in[8];
  const float* bc = (const float*)d_in[9];

  float* ws = (float*)d_ws;
  float* q  = ws;                       // 320*512
  float* k  = ws + NC * DIM;            // 320*512
  float* S  = ws + 2 * NC * DIM;        // 320*320
  float* P  = S + NC * NC;              // 320
  float* h  = P + NC;                   // 512
  float* out = (float*)d_out;

  hipMemsetAsync(P, 0, (NC + DIM) * sizeof(float), stream);
  hipMemsetAsync(out, 0, sizeof(float), stream);

  gemm_qk2<<<dim3(8, 20, 2), 256, 0, stream>>>(x, Wq, bq, Wk, bk, q, k);
  compute_h<<<dim3(2, 16), 256, 0, stream>>>(Wv, Wc, h);
  scores<<<dim3(20, 20), 256, 0, stream>>>(q, k, S);
  row_ops<<<NC, 256, 0, stream>>>(S, P);
  finalize<<<NC, 256, 0, stream>>>(x, P, h, Wc, bc, bv, out);
}